// Round 4
// baseline (2072.587 us; speedup 1.0000x reference)
//
#include <hip/hip_runtime.h>
#include <hip/hip_bf16.h>
#include <math.h>

typedef unsigned short us;
typedef short bf16x8 __attribute__((ext_vector_type(8)));
typedef float f32x4 __attribute__((ext_vector_type(4)));
typedef unsigned short usx4 __attribute__((ext_vector_type(4)));

#define NT   2048   // B*T tokens
#define DDIM 1024
#define FF   4096
#define TT   1024
#define NH   16
#define CL   1023   // T - n_non_bias_tokens

__device__ __forceinline__ us f2bf(float f) {
  unsigned u = __float_as_uint(f);
  return (us)((u + 0x7FFFu + ((u >> 16) & 1u)) >> 16);
}

// async global->LDS, 16B per lane; lds base must be wave-uniform [m97 pattern]
__device__ __forceinline__ void gld_lds16(const us* g, us* l) {
  __builtin_amdgcn_global_load_lds(
      (const __attribute__((address_space(1))) unsigned int*)(g),
      (__attribute__((address_space(3))) unsigned int*)(l), 16, 0, 0);
}

// ---------------- cast kernels ----------------
__device__ __forceinline__ void cast_seg(const float* s, us* d, int n4, int tid, int stride) {
  if (n4 <= 0) return;
  for (int i = tid; i < n4; i += stride) {
    float4 v = ((const float4*)s)[i];
    usx4 o; o.x = f2bf(v.x); o.y = f2bf(v.y); o.z = f2bf(v.z); o.w = f2bf(v.w);
    ((usx4*)d)[i] = o;
  }
}

__global__ void cast5_kernel(const float* s0, us* d0, int n0,
                             const float* s1, us* d1, int n1,
                             const float* s2, us* d2, int n2,
                             const float* s3, us* d3, int n3,
                             const float* s4, us* d4, int n4) {
  int tid = blockIdx.x * blockDim.x + threadIdx.x;
  int stride = gridDim.x * blockDim.x;
  cast_seg(s0, d0, n0, tid, stride);
  cast_seg(s1, d1, n1, tid, stride);
  cast_seg(s2, d2, n2, tid, stride);
  cast_seg(s3, d3, n3, tid, stride);
  cast_seg(s4, d4, n4, tid, stride);
}

__global__ void cast1_kernel(const float* s, us* d, int n4) {
  int tid = blockIdx.x * blockDim.x + threadIdx.x;
  int stride = gridDim.x * blockDim.x;
  cast_seg(s, d, n4, tid, stride);
}

// ---------------- 4-wave MFMA GEMM: BM=64, BN in {64,128}, BK=32 ----
// block: 256 thr. BN=128: wave tile 32x64 (acc 2x4). BN=64: wave tile 32x32 (acc 2x2).
// MODE 2: outb = bf16(gelu(acc + bias))                       (MLP-in)
// MODE 5: QKV fused epilogue -> Qb/Kb (bhtd, Q*0.125), Vt (bhdt)
// MODE 7: outf += acc  (non-atomic z=1 residual add)          (attn-out)
// MODE 8: v = acc + bias + outf; outf = v; outb = bf16(v)     (MLP-out, fuses bias+resid+cast)
// MODE 9: v = acc + bias;        outf = v; outb = bf16(v)     (skip, fuses bias+cast)
template<int MODE, int BN>
__global__ __launch_bounds__(256)
void gemm4(const us* __restrict__ A, const us* __restrict__ W,
           const float* __restrict__ bias, float* outf, us* outb,
           us* __restrict__ Qb, us* __restrict__ Kb, us* __restrict__ Vt,
           int M, int N, int K, int kchunk)
{
  __shared__ us As[64 * 32];
  __shared__ us Ws[BN * 32];
  const int tid = threadIdx.x;
  const int m0 = blockIdx.y * 64, n0 = blockIdx.x * BN;
  const int wave = tid >> 6, lane = tid & 63;
  const int wm = (wave & 1) * 32, wn = (wave >> 1) * (BN >> 1);
  const int frow = lane & 15, fk = (lane >> 4) * 8;
  const int kbeg = blockIdx.z * kchunk, kend = kbeg + kchunk;
  const int ar = tid >> 2, ac = (tid & 3) * 8;      // stage: row tid/4, col-8chunk
  const int wr1 = (256 + tid) >> 2;
  constexpr int NJ = BN / 32;                       // acc cols: 4 (BN=128) or 2 (BN=64)
  f32x4 acc[2][NJ] = {};
  for (int k0 = kbeg; k0 < kend; k0 += 32) {
    // staging: LDS linear order == lane order (wave-uniform base, m97/m104)
    gld_lds16(A + (size_t)(m0 + ar) * K + k0 + ac, As + wave * 512);
    gld_lds16(W + (size_t)(n0 + ar) * K + k0 + ac, Ws + wave * 512);
    if (BN == 128)
      gld_lds16(W + (size_t)(n0 + wr1) * K + k0 + ac, Ws + 2048 + wave * 512);
    __syncthreads();
    bf16x8 afr[2], wfr[NJ];
    #pragma unroll
    for (int i = 0; i < 2; ++i) afr[i] = *(const bf16x8*)(As + (wm + i * 16 + frow) * 32 + fk);
    #pragma unroll
    for (int j = 0; j < NJ; ++j) wfr[j] = *(const bf16x8*)(Ws + (wn + j * 16 + frow) * 32 + fk);
    #pragma unroll
    for (int i = 0; i < 2; ++i)
      #pragma unroll
      for (int j = 0; j < NJ; ++j)
        acc[i][j] = __builtin_amdgcn_mfma_f32_16x16x32_bf16(afr[i], wfr[j], acc[i][j], 0, 0, 0);
    __syncthreads();
  }
  // epilogue: C/D layout col=lane&15, row=(lane>>4)*4+reg [m89/m91]
  const int col = lane & 15, rq = (lane >> 4) * 4;
  #pragma unroll
  for (int i = 0; i < 2; ++i) {
    const int gmq = m0 + wm + i * 16 + rq;   // first of 4 consecutive token rows
    #pragma unroll
    for (int j = 0; j < NJ; ++j) {
      const int gn = n0 + wn + j * 16 + col;
      if (MODE == 5) {
        const int t = gmq & (TT - 1), b = gmq >> 10;   // BM=64 tile never straddles batch
        if (gn < DDIM) {
          const int h = gn >> 6, d = gn & 63;
          us* qp = Qb + ((size_t)(b * NH + h) * TT + t) * 64 + d;
          #pragma unroll
          for (int r = 0; r < 4; ++r) qp[(size_t)r * 64] = f2bf(acc[i][j][r] * 0.125f);
        } else if (gn < 2 * DDIM) {
          const int h = (gn - DDIM) >> 6, d = gn & 63;
          us* kp = Kb + ((size_t)(b * NH + h) * TT + t) * 64 + d;
          #pragma unroll
          for (int r = 0; r < 4; ++r) kp[(size_t)r * 64] = f2bf(acc[i][j][r]);
        } else {
          const int h = (gn - 2 * DDIM) >> 6, d = gn & 63;
          usx4 o;
          o.x = f2bf(acc[i][j][0]); o.y = f2bf(acc[i][j][1]);
          o.z = f2bf(acc[i][j][2]); o.w = f2bf(acc[i][j][3]);
          *(usx4*)(Vt + ((size_t)(b * NH + h) * 64 + d) * TT + t) = o;
        }
      } else {
        #pragma unroll
        for (int r = 0; r < 4; ++r) {
          const size_t oi = (size_t)(gmq + r) * N + gn;
          float v = acc[i][j][r];
          if (MODE == 2) {
            float tb = v + bias[gn];
            outb[oi] = f2bf(0.5f * tb * (1.0f + erff(tb * 0.70710678118654752f)));
          }
          if (MODE == 7) {
            outf[oi] = v + outf[oi];
          }
          if (MODE == 8) {
            float w = v + bias[gn] + outf[oi];
            outf[oi] = w; outb[oi] = f2bf(w);
          }
          if (MODE == 9) {
            float w = v + bias[gn];
            outf[oi] = w; outb[oi] = f2bf(w);
          }
        }
      }
    }
  }
}

// ---------------- MFMA flash attention (barrier-free, K/V direct from L2) ----
// block: 256 thr (4 waves), one (b,h), 64 q rows; wave w owns q rows [q0+16w, +16)
// K/V per (b,h) = 256 KB total -> L2-resident (written by QKV GEMM just before).
// No LDS staging, no __syncthreads: waves fully independent [m169 pattern].
__global__ __launch_bounds__(256)
void attn_mfma_kernel(const us* __restrict__ Qb, const us* __restrict__ Kb,
                      const us* __restrict__ Vt, us* __restrict__ obf) {
  __shared__ us Ps[4][16 * 72];    // per-wave P [q][key], pad 72 (no cross-wave use)
  const int bh = blockIdx.y;
  const int h = bh & (NH - 1), b = bh >> 4;
  const int q0 = blockIdx.x * 64;
  const int tid = threadIdx.x, wave = tid >> 6, lane = tid & 63;
  const float slope = -exp2f(-0.5f * (float)(h + 1));
  const size_t kvbase = (size_t)bh * TT * 64;
  const size_t vtbase = (size_t)bh * 64 * TT;
  const int col = lane & 15, grp = lane >> 4, rq = grp * 4;
  const int qbase = q0 + wave * 16;
  us* Psw = Ps[wave];
  bf16x8 qfrag[2];
  {
    const us* qp = Qb + kvbase + (size_t)(qbase + col) * 64 + grp * 8;
    qfrag[0] = *(const bf16x8*)(qp);
    qfrag[1] = *(const bf16x8*)(qp + 32);
  }
  f32x4 Oacc[4] = {};   // O[q=rq+r][d=ni*16+col]
  float mrow[4], lrow[4];
  #pragma unroll
  for (int r = 0; r < 4; ++r) { mrow[r] = -3e38f; lrow[r] = 0.0f; }
  for (int kt = 0; kt < 16; ++kt) {
    const int k0 = kt * 64;
    f32x4 sacc[4];
    #pragma unroll
    for (int ni = 0; ni < 4; ++ni) {
      // K fragment straight from global: key=k0+ni*16+col, d=grp*8(+32)
      const us* kp = Kb + kvbase + (size_t)(k0 + ni * 16 + col) * 64 + grp * 8;
      bf16x8 kf0 = *(const bf16x8*)(kp);
      bf16x8 kf1 = *(const bf16x8*)(kp + 32);
      f32x4 a = {};
      a = __builtin_amdgcn_mfma_f32_16x16x32_bf16(qfrag[0], kf0, a, 0, 0, 0);
      a = __builtin_amdgcn_mfma_f32_16x16x32_bf16(qfrag[1], kf1, a, 0, 0, 0);
      sacc[ni] = a;
    }
    float pmax[4];
    #pragma unroll
    for (int r = 0; r < 4; ++r) pmax[r] = -3e38f;
    #pragma unroll
    for (int ni = 0; ni < 4; ++ni) {
      int kglob = k0 + ni * 16 + col;
      #pragma unroll
      for (int r = 0; r < 4; ++r) {
        int qglob = qbase + rq + r;
        float ab = (qglob < CL && kglob < CL) ? slope * fabsf((float)(kglob - qglob)) : 0.0f;
        sacc[ni][r] += ab;
        pmax[r] = fmaxf(pmax[r], sacc[ni][r]);
      }
    }
    #pragma unroll
    for (int off = 1; off < 16; off <<= 1)
      #pragma unroll
      for (int r = 0; r < 4; ++r)
        pmax[r] = fmaxf(pmax[r], __shfl_xor(pmax[r], off, 64));
    float alpha[4], psum[4];
    #pragma unroll
    for (int r = 0; r < 4; ++r) {
      float mnew = fmaxf(mrow[r], pmax[r]);
      alpha[r] = __expf(mrow[r] - mnew);
      mrow[r] = mnew;
      psum[r] = 0.0f;
    }
    #pragma unroll
    for (int ni = 0; ni < 4; ++ni)
      #pragma unroll
      for (int r = 0; r < 4; ++r) {
        float pv = __expf(sacc[ni][r] - mrow[r]);
        psum[r] += pv;
        Psw[(rq + r) * 72 + ni * 16 + col] = f2bf(pv);
      }
    #pragma unroll
    for (int off = 1; off < 16; off <<= 1)
      #pragma unroll
      for (int r = 0; r < 4; ++r)
        psum[r] += __shfl_xor(psum[r], off, 64);
    #pragma unroll
    for (int r = 0; r < 4; ++r) lrow[r] = alpha[r] * lrow[r] + psum[r];
    #pragma unroll
    for (int ni = 0; ni < 4; ++ni)
      #pragma unroll
      for (int r = 0; r < 4; ++r) Oacc[ni][r] *= alpha[r];
    // per-wave LDS round-trip only; compiler inserts lgkmcnt, no barrier needed
    bf16x8 pf0 = *(const bf16x8*)(Psw + col * 72 + grp * 8);
    bf16x8 pf1 = *(const bf16x8*)(Psw + col * 72 + 32 + grp * 8);
    #pragma unroll
    for (int ni = 0; ni < 4; ++ni) {
      // V fragment straight from global: d=ni*16+col, key offset grp*8(+32)
      const us* vp = Vt + vtbase + (size_t)(ni * 16 + col) * TT + k0 + grp * 8;
      bf16x8 vf0 = *(const bf16x8*)(vp);
      bf16x8 vf1 = *(const bf16x8*)(vp + 32);
      Oacc[ni] = __builtin_amdgcn_mfma_f32_16x16x32_bf16(pf0, vf0, Oacc[ni], 0, 0, 0);
      Oacc[ni] = __builtin_amdgcn_mfma_f32_16x16x32_bf16(pf1, vf1, Oacc[ni], 0, 0, 0);
    }
  }
  #pragma unroll
  for (int ni = 0; ni < 4; ++ni)
    #pragma unroll
    for (int r = 0; r < 4; ++r) {
      size_t token = (size_t)b * TT + qbase + rq + r;
      obf[token * DDIM + h * 64 + ni * 16 + col] = f2bf(Oacc[ni][r] / lrow[r]);
    }
}

// ---------------- LayerNorm (gain only, eps=1e-5), fp32 or bf16 out ----------------
template<int BF16OUT>
__global__ __launch_bounds__(256)
void ln_kernel(const float* __restrict__ x, const float* __restrict__ g,
               float* outf, us* outb) {
  __shared__ float red[256];
  const int rowi = blockIdx.x, t = threadIdx.x;
  const float* xr = x + (size_t)rowi * DDIM;
  float4 v = ((const float4*)xr)[t];
  red[t] = v.x + v.y + v.z + v.w;
  __syncthreads();
  for (int off = 128; off > 0; off >>= 1) {
    if (t < off) red[t] += red[t + off];
    __syncthreads();
  }
  float mu = red[0] * (1.0f / 1024.0f);
  __syncthreads();
  float dx = v.x - mu, dy = v.y - mu, dz = v.z - mu, dw = v.w - mu;
  red[t] = dx * dx + dy * dy + dz * dz + dw * dw;
  __syncthreads();
  for (int off = 128; off > 0; off >>= 1) {
    if (t < off) red[t] += red[t + off];
    __syncthreads();
  }
  float rs = rsqrtf(red[0] * (1.0f / 1024.0f) + 1e-5f);
  float4 gg = ((const float4*)g)[t];
  if (BF16OUT) {
    usx4 o;
    o.x = f2bf(dx * rs * gg.x); o.y = f2bf(dy * rs * gg.y);
    o.z = f2bf(dz * rs * gg.z); o.w = f2bf(dw * rs * gg.w);
    ((usx4*)(outb + (size_t)rowi * DDIM))[t] = o;
  } else {
    float4 o;
    o.x = dx * rs * gg.x; o.y = dy * rs * gg.y; o.z = dz * rs * gg.z; o.w = dw * rs * gg.w;
    ((float4*)(outf + (size_t)rowi * DDIM))[t] = o;
  }
}

// ---------------- concat [x, s*2^-0.5] -> bf16 [NT, 2048] ----------------
__global__ void concat_cast_kernel(const float* __restrict__ x, const float* __restrict__ s,
                                   us* __restrict__ out) {
  int i4 = blockIdx.x * blockDim.x + threadIdx.x;  // 1048576 threads
  int e = i4 * 4;
  int r = e >> 11, c = e & 2047;
  float4 v;
  if (c < DDIM) {
    v = *(const float4*)(x + (size_t)r * DDIM + c);
  } else {
    v = *(const float4*)(s + (size_t)r * DDIM + (c - DDIM));
    v.x *= 0.70710678118654752f; v.y *= 0.70710678118654752f;
    v.z *= 0.70710678118654752f; v.w *= 0.70710678118654752f;
  }
  usx4 o; o.x = f2bf(v.x); o.y = f2bf(v.y); o.z = f2bf(v.z); o.w = f2bf(v.w);
  ((usx4*)out)[i4] = o;
}

// ---------------- launch ----------------
extern "C" void kernel_launch(void* const* d_in, const int* in_sizes, int n_in,
                              void* d_out, int out_size, void* d_ws, size_t ws_size,
                              hipStream_t stream) {
  (void)in_sizes; (void)n_in; (void)out_size; (void)ws_size;
  const float* x_in       = (const float*)d_in[0];
  const float* attn_w     = (const float*)d_in[1];
  const float* attn_out_w = (const float*)d_in[2];
  const float* mlp_ln_g   = (const float*)d_in[3];
  const float* mlp_in_w   = (const float*)d_in[4];
  const float* mlp_in_b   = (const float*)d_in[5];
  const float* mlp_out_w  = (const float*)d_in[6];
  const float* mlp_out_b  = (const float*)d_in[7];
  const float* skip_w     = (const float*)d_in[8];
  const float* skip_b     = (const float*)d_in[9];
  const float* out_ln_g   = (const float*)d_in[10];

  char* p = (char*)d_ws;
  auto alloc = [&](size_t bytes) { char* r = p; p += (bytes + 255) & ~(size_t)255; return r; };
  float* xbuf = (float*)alloc((size_t)NT * DDIM * 4);
  float* conn = (float*)alloc((size_t)3 * NT * DDIM * 4);
  us* Qb   = (us*)alloc((size_t)NT * DDIM * 2);
  us* Kb   = (us*)alloc((size_t)NT * DDIM * 2);
  us* Vt   = (us*)alloc((size_t)NT * DDIM * 2);
  us* xbf  = (us*)alloc((size_t)NT * DDIM * 2);
  us* obf  = (us*)alloc((size_t)NT * DDIM * 2);
  us* hln  = (us*)alloc((size_t)NT * DDIM * 2);
  us* hbf  = (us*)alloc((size_t)NT * FF * 2);
  us* xcbf = (us*)alloc((size_t)NT * 2 * DDIM * 2);
  us* wqkv = (us*)alloc((size_t)3 * DDIM * DDIM * 2);
  us* wao  = (us*)alloc((size_t)DDIM * DDIM * 2);
  us* wmi  = (us*)alloc((size_t)FF * DDIM * 2);
  us* wmo  = (us*)alloc((size_t)DDIM * FF * 2);
  us* wsk  = (us*)alloc((size_t)DDIM * 2 * DDIM * 2);

  hipMemcpyAsync(xbuf, x_in, (size_t)NT * DDIM * 4, hipMemcpyDeviceToDevice, stream);
  cast1_kernel<<<1024, 256, 0, stream>>>(x_in, xbf, NT * DDIM / 4);

  for (int i = 0; i < 8; ++i) {
    const int do_skip = (i >= 5);
    cast5_kernel<<<1024, 256, 0, stream>>>(
        attn_w + (size_t)i * 3 * DDIM * DDIM, wqkv, 3 * DDIM * DDIM / 4,
        attn_out_w + (size_t)i * DDIM * DDIM, wao, DDIM * DDIM / 4,
        mlp_in_w + (size_t)i * FF * DDIM, wmi, FF * DDIM / 4,
        mlp_out_w + (size_t)i * DDIM * FF, wmo, DDIM * FF / 4,
        do_skip ? (skip_w + (size_t)(i - 4) * DDIM * 2 * DDIM) : nullptr, wsk,
        do_skip ? (DDIM * 2 * DDIM / 4) : 0);
    if (do_skip) {
      concat_cast_kernel<<<4096, 256, 0, stream>>>(xbuf, conn + (size_t)(7 - i) * NT * DDIM, xcbf);
      // skip GEMM: x = xc @ Wsk^T + skip_b; writes fp32 xbuf + bf16 xbf (fused cast)
      gemm4<9, 64><<<dim3(16, 32, 1), 256, 0, stream>>>(
          xcbf, wsk, skip_b + (size_t)(i - 4) * DDIM, xbuf, xbf, nullptr, nullptr, nullptr,
          NT, DDIM, 2 * DDIM, 2 * DDIM);
    }
    gemm4<5, 128><<<dim3(24, 32, 1), 256, 0, stream>>>(
        xbf, wqkv, nullptr, nullptr, nullptr, Qb, Kb, Vt,
        NT, 3 * DDIM, DDIM, DDIM);
    attn_mfma_kernel<<<dim3(TT / 64, 2 * NH), 256, 0, stream>>>(Qb, Kb, Vt, obf);
    // attn-out GEMM: xbuf += obf @ Wao^T (non-atomic, z=1)
    gemm4<7, 64><<<dim3(16, 32, 1), 256, 0, stream>>>(
        obf, wao, nullptr, xbuf, nullptr, nullptr, nullptr, nullptr,
        NT, DDIM, DDIM, DDIM);
    ln_kernel<1><<<NT, 256, 0, stream>>>(xbuf, mlp_ln_g + (size_t)i * DDIM, nullptr, hln);
    gemm4<2, 128><<<dim3(32, 32, 1), 256, 0, stream>>>(
        hln, wmi, mlp_in_b + (size_t)i * FF, nullptr, hbf, nullptr, nullptr, nullptr,
        NT, FF, DDIM, DDIM);
    // MLP-out GEMM: x = x + h @ Wmo^T + b; writes fp32 xbuf + bf16 xbf (fused bias+resid+cast)
    gemm4<8, 64><<<dim3(16, 32, 1), 256, 0, stream>>>(
        hbf, wmo, mlp_out_b + (size_t)i * DDIM, xbuf, xbf, nullptr, nullptr, nullptr,
        NT, DDIM, FF, FF);
    if (i >= 2 && i <= 4)
      hipMemcpyAsync(conn + (size_t)(i - 2) * NT * DDIM, xbuf, (size_t)NT * DDIM * 4,
                     hipMemcpyDeviceToDevice, stream);
  }
  ln_kernel<0><<<NT, 256, 0, stream>>>(xbuf, out_ln_g, (float*)d_out, nullptr);
}

// Round 5
// 1902.804 us; speedup vs baseline: 1.0892x; 1.0892x over previous
//
#include <hip/hip_runtime.h>
#include <hip/hip_bf16.h>
#include <math.h>

typedef unsigned short us;
typedef short bf16x8 __attribute__((ext_vector_type(8)));
typedef float f32x4 __attribute__((ext_vector_type(4)));
typedef unsigned short usx4 __attribute__((ext_vector_type(4)));

#define NT   2048   // B*T tokens
#define DDIM 1024
#define FF   4096
#define TT   1024
#define NH   16
#define CL   1023   // T - n_non_bias_tokens

__device__ __forceinline__ us f2bf(float f) {
  unsigned u = __float_as_uint(f);
  return (us)((u + 0x7FFFu + ((u >> 16) & 1u)) >> 16);
}

// async global->LDS, 16B per lane; lds base must be wave-uniform [m97 pattern]
__device__ __forceinline__ void gld_lds16(const us* g, us* l) {
  __builtin_amdgcn_global_load_lds(
      (const __attribute__((address_space(1))) unsigned int*)(g),
      (__attribute__((address_space(3))) unsigned int*)(l), 16, 0, 0);
}

// ---------------- cast kernels ----------------
__device__ __forceinline__ void cast_seg(const float* s, us* d, int n4, int tid, int stride) {
  if (n4 <= 0) return;
  for (int i = tid; i < n4; i += stride) {
    float4 v = ((const float4*)s)[i];
    usx4 o; o.x = f2bf(v.x); o.y = f2bf(v.y); o.z = f2bf(v.z); o.w = f2bf(v.w);
    ((usx4*)d)[i] = o;
  }
}

// skip-weight cast: fold the 2^-0.5 connection scale into columns e>=1024 of Wsk [D,2D]
__device__ __forceinline__ void cast_seg_skipw(const float* s, us* d, int n4, int tid, int stride) {
  if (n4 <= 0) return;
  for (int i = tid; i < n4; i += stride) {
    float4 v = ((const float4*)s)[i];
    float sc = (((i * 4) & 2047) >= 1024) ? 0.70710678118654752f : 1.0f;
    usx4 o; o.x = f2bf(v.x * sc); o.y = f2bf(v.y * sc);
    o.z = f2bf(v.z * sc); o.w = f2bf(v.w * sc);
    ((usx4*)d)[i] = o;
  }
}

__global__ void cast5_kernel(const float* s0, us* d0, int n0,
                             const float* s1, us* d1, int n1,
                             const float* s2, us* d2, int n2,
                             const float* s3, us* d3, int n3,
                             const float* s4, us* d4, int n4) {
  int tid = blockIdx.x * blockDim.x + threadIdx.x;
  int stride = gridDim.x * blockDim.x;
  cast_seg(s0, d0, n0, tid, stride);
  cast_seg(s1, d1, n1, tid, stride);
  cast_seg(s2, d2, n2, tid, stride);
  cast_seg(s3, d3, n3, tid, stride);
  cast_seg_skipw(s4, d4, n4, tid, stride);
}

__global__ void cast1_kernel(const float* s, us* d, int n4) {
  int tid = blockIdx.x * blockDim.x + threadIdx.x;
  int stride = gridDim.x * blockDim.x;
  cast_seg(s, d, n4, tid, stride);
}

// ---------------- 4-wave MFMA GEMM: BM=64, BN in {64,128}, BK=32 ----
// block: 256 thr. BN=128: wave tile 32x64 (acc 2x4). BN=64: wave tile 32x32 (acc 2x2).
// MODE 2: outb = bf16(gelu(acc + bias))                       (MLP-in)
// MODE 5: QKV fused epilogue -> Qb/Kb (bhtd, Q*0.125), Vt (bhdt)
// MODE 7: outf += acc  (non-atomic z=1 residual add)          (attn-out)
// MODE 8: v = acc + bias + outf; outf = v; outb = bf16(v)     (MLP-out, fuses bias+resid+cast)
// MODE 9: v = acc + bias;        outf = v; outb = bf16(v)     (skip; A split: k<1024 from A, else A2)
template<int MODE, int BN>
__global__ __launch_bounds__(256)
void gemm4(const us* __restrict__ A, const us* __restrict__ A2, const us* __restrict__ W,
           const float* __restrict__ bias, float* outf, us* outb,
           us* __restrict__ Qb, us* __restrict__ Kb, us* __restrict__ Vt,
           int M, int N, int K, int kchunk, int lda)
{
  __shared__ us As[64 * 32];
  __shared__ us Ws[BN * 32];
  const int tid = threadIdx.x;
  const int m0 = blockIdx.y * 64, n0 = blockIdx.x * BN;
  const int wave = tid >> 6, lane = tid & 63;
  const int wm = (wave & 1) * 32, wn = (wave >> 1) * (BN >> 1);
  const int frow = lane & 15, fk = (lane >> 4) * 8;
  const int kbeg = blockIdx.z * kchunk, kend = kbeg + kchunk;
  const int ar = tid >> 2, ac = (tid & 3) * 8;      // stage: row tid/4, col-8chunk
  const int wr1 = (256 + tid) >> 2;
  constexpr int NJ = BN / 32;                       // acc cols: 4 (BN=128) or 2 (BN=64)
  f32x4 acc[2][NJ] = {};
  for (int k0 = kbeg; k0 < kend; k0 += 32) {
    // staging: LDS linear order == lane order (wave-uniform base, m97/m104)
    const us* Ab; int ka;
    if (MODE == 9) { Ab = (k0 < DDIM) ? A : A2; ka = k0 & (DDIM - 1); }
    else { Ab = A; ka = k0; }
    gld_lds16(Ab + (size_t)(m0 + ar) * lda + ka + ac, As + wave * 512);
    gld_lds16(W + (size_t)(n0 + ar) * K + k0 + ac, Ws + wave * 512);
    if (BN == 128)
      gld_lds16(W + (size_t)(n0 + wr1) * K + k0 + ac, Ws + 2048 + wave * 512);
    __syncthreads();
    bf16x8 afr[2], wfr[NJ];
    #pragma unroll
    for (int i = 0; i < 2; ++i) afr[i] = *(const bf16x8*)(As + (wm + i * 16 + frow) * 32 + fk);
    #pragma unroll
    for (int j = 0; j < NJ; ++j) wfr[j] = *(const bf16x8*)(Ws + (wn + j * 16 + frow) * 32 + fk);
    #pragma unroll
    for (int i = 0; i < 2; ++i)
      #pragma unroll
      for (int j = 0; j < NJ; ++j)
        acc[i][j] = __builtin_amdgcn_mfma_f32_16x16x32_bf16(afr[i], wfr[j], acc[i][j], 0, 0, 0);
    __syncthreads();
  }
  // epilogue: C/D layout col=lane&15, row=(lane>>4)*4+reg [m89/m91]
  const int col = lane & 15, rq = (lane >> 4) * 4;
  #pragma unroll
  for (int i = 0; i < 2; ++i) {
    const int gmq = m0 + wm + i * 16 + rq;   // first of 4 consecutive token rows
    #pragma unroll
    for (int j = 0; j < NJ; ++j) {
      const int gn = n0 + wn + j * 16 + col;
      if (MODE == 5) {
        const int t = gmq & (TT - 1), b = gmq >> 10;   // BM=64 tile never straddles batch
        if (gn < DDIM) {
          const int h = gn >> 6, d = gn & 63;
          us* qp = Qb + ((size_t)(b * NH + h) * TT + t) * 64 + d;
          #pragma unroll
          for (int r = 0; r < 4; ++r) qp[(size_t)r * 64] = f2bf(acc[i][j][r] * 0.125f);
        } else if (gn < 2 * DDIM) {
          const int h = (gn - DDIM) >> 6, d = gn & 63;
          us* kp = Kb + ((size_t)(b * NH + h) * TT + t) * 64 + d;
          #pragma unroll
          for (int r = 0; r < 4; ++r) kp[(size_t)r * 64] = f2bf(acc[i][j][r]);
        } else {
          const int h = (gn - 2 * DDIM) >> 6, d = gn & 63;
          usx4 o;
          o.x = f2bf(acc[i][j][0]); o.y = f2bf(acc[i][j][1]);
          o.z = f2bf(acc[i][j][2]); o.w = f2bf(acc[i][j][3]);
          *(usx4*)(Vt + ((size_t)(b * NH + h) * 64 + d) * TT + t) = o;
        }
      } else {
        #pragma unroll
        for (int r = 0; r < 4; ++r) {
          const size_t oi = (size_t)(gmq + r) * N + gn;
          float v = acc[i][j][r];
          if (MODE == 2) {
            float tb = v + bias[gn];
            outb[oi] = f2bf(0.5f * tb * (1.0f + erff(tb * 0.70710678118654752f)));
          }
          if (MODE == 7) {
            outf[oi] = v + outf[oi];
          }
          if (MODE == 8) {
            float w = v + bias[gn] + outf[oi];
            outf[oi] = w; outb[oi] = f2bf(w);
          }
          if (MODE == 9) {
            float w = v + bias[gn];
            outf[oi] = w; outb[oi] = f2bf(w);
          }
        }
      }
    }
  }
}

// ---------------- MFMA flash attention (round-2 proven: LDS-staged K/V) ----
// block: 256 thr (4 waves), one (b,h), 64 q rows; wave w owns q rows [q0+16w, +16)
__global__ __launch_bounds__(256)
void attn_mfma_kernel(const us* __restrict__ Qb, const us* __restrict__ Kb,
                      const us* __restrict__ Vt, us* __restrict__ obf) {
  __shared__ us Ks[64 * 72];       // [key][d], pad 72
  __shared__ us Vs[64 * 72];       // [d][key], pad 72
  __shared__ us Ps[4][16 * 72];    // per-wave P [q][key]
  const int bh = blockIdx.y;
  const int h = bh & (NH - 1), b = bh >> 4;
  const int q0 = blockIdx.x * 64;
  const int tid = threadIdx.x, wave = tid >> 6, lane = tid & 63;
  const float slope = -exp2f(-0.5f * (float)(h + 1));
  const size_t kvbase = (size_t)bh * TT * 64;
  const size_t vtbase = (size_t)bh * 64 * TT;
  const int col = lane & 15, grp = lane >> 4, rq = grp * 4;
  const int qbase = q0 + wave * 16;
  us* Psw = Ps[wave];
  bf16x8 qfrag[2];
  {
    const us* qp = Qb + kvbase + (size_t)(qbase + col) * 64 + grp * 8;
    qfrag[0] = *(const bf16x8*)(qp);
    qfrag[1] = *(const bf16x8*)(qp + 32);
  }
  f32x4 Oacc[4] = {};   // O[q=rq+r][d=ni*16+col]
  float mrow[4], lrow[4];
  #pragma unroll
  for (int r = 0; r < 4; ++r) { mrow[r] = -3e38f; lrow[r] = 0.0f; }
  for (int kt = 0; kt < 16; ++kt) {
    const int k0 = kt * 64;
    __syncthreads();
    #pragma unroll
    for (int p = 0; p < 2; ++p) {
      int idx = tid * 8 + p * 2048;
      int r = idx >> 6, c = idx & 63;
      *(bf16x8*)(Ks + r * 72 + c) = *(const bf16x8*)(Kb + kvbase + (size_t)(k0 + r) * 64 + c);
      *(bf16x8*)(Vs + r * 72 + c) = *(const bf16x8*)(Vt + vtbase + (size_t)r * TT + k0 + c);
    }
    __syncthreads();
    f32x4 sacc[4];
    #pragma unroll
    for (int ni = 0; ni < 4; ++ni) {
      const us* kp = Ks + (ni * 16 + col) * 72 + grp * 8;
      bf16x8 kf0 = *(const bf16x8*)(kp);
      bf16x8 kf1 = *(const bf16x8*)(kp + 32);
      f32x4 a = {};
      a = __builtin_amdgcn_mfma_f32_16x16x32_bf16(qfrag[0], kf0, a, 0, 0, 0);
      a = __builtin_amdgcn_mfma_f32_16x16x32_bf16(qfrag[1], kf1, a, 0, 0, 0);
      sacc[ni] = a;
    }
    float pmax[4];
    #pragma unroll
    for (int r = 0; r < 4; ++r) pmax[r] = -3e38f;
    #pragma unroll
    for (int ni = 0; ni < 4; ++ni) {
      int kglob = k0 + ni * 16 + col;
      #pragma unroll
      for (int r = 0; r < 4; ++r) {
        int qglob = qbase + rq + r;
        float ab = (qglob < CL && kglob < CL) ? slope * fabsf((float)(kglob - qglob)) : 0.0f;
        sacc[ni][r] += ab;
        pmax[r] = fmaxf(pmax[r], sacc[ni][r]);
      }
    }
    #pragma unroll
    for (int off = 1; off < 16; off <<= 1)
      #pragma unroll
      for (int r = 0; r < 4; ++r)
        pmax[r] = fmaxf(pmax[r], __shfl_xor(pmax[r], off, 64));
    float alpha[4], psum[4];
    #pragma unroll
    for (int r = 0; r < 4; ++r) {
      float mnew = fmaxf(mrow[r], pmax[r]);
      alpha[r] = __expf(mrow[r] - mnew);
      mrow[r] = mnew;
      psum[r] = 0.0f;
    }
    #pragma unroll
    for (int ni = 0; ni < 4; ++ni)
      #pragma unroll
      for (int r = 0; r < 4; ++r) {
        float pv = __expf(sacc[ni][r] - mrow[r]);
        psum[r] += pv;
        Psw[(rq + r) * 72 + ni * 16 + col] = f2bf(pv);
      }
    #pragma unroll
    for (int off = 1; off < 16; off <<= 1)
      #pragma unroll
      for (int r = 0; r < 4; ++r)
        psum[r] += __shfl_xor(psum[r], off, 64);
    #pragma unroll
    for (int r = 0; r < 4; ++r) lrow[r] = alpha[r] * lrow[r] + psum[r];
    #pragma unroll
    for (int ni = 0; ni < 4; ++ni)
      #pragma unroll
      for (int r = 0; r < 4; ++r) Oacc[ni][r] *= alpha[r];
    bf16x8 pf0 = *(const bf16x8*)(Psw + col * 72 + grp * 8);
    bf16x8 pf1 = *(const bf16x8*)(Psw + col * 72 + 32 + grp * 8);
    #pragma unroll
    for (int ni = 0; ni < 4; ++ni) {
      const us* vp = Vs + (ni * 16 + col) * 72 + grp * 8;
      bf16x8 vf0 = *(const bf16x8*)(vp);
      bf16x8 vf1 = *(const bf16x8*)(vp + 32);
      Oacc[ni] = __builtin_amdgcn_mfma_f32_16x16x32_bf16(pf0, vf0, Oacc[ni], 0, 0, 0);
      Oacc[ni] = __builtin_amdgcn_mfma_f32_16x16x32_bf16(pf1, vf1, Oacc[ni], 0, 0, 0);
    }
  }
  #pragma unroll
  for (int ni = 0; ni < 4; ++ni)
    #pragma unroll
    for (int r = 0; r < 4; ++r) {
      size_t token = (size_t)b * TT + qbase + rq + r;
      obf[token * DDIM + h * 64 + ni * 16 + col] = f2bf(Oacc[ni][r] / lrow[r]);
    }
}

// ---------------- LayerNorm (gain only, eps=1e-5), fp32 or bf16 out ----------------
template<int BF16OUT>
__global__ __launch_bounds__(256)
void ln_kernel(const float* __restrict__ x, const float* __restrict__ g,
               float* outf, us* outb) {
  __shared__ float red[256];
  const int rowi = blockIdx.x, t = threadIdx.x;
  const float* xr = x + (size_t)rowi * DDIM;
  float4 v = ((const float4*)xr)[t];
  red[t] = v.x + v.y + v.z + v.w;
  __syncthreads();
  for (int off = 128; off > 0; off >>= 1) {
    if (t < off) red[t] += red[t + off];
    __syncthreads();
  }
  float mu = red[0] * (1.0f / 1024.0f);
  __syncthreads();
  float dx = v.x - mu, dy = v.y - mu, dz = v.z - mu, dw = v.w - mu;
  red[t] = dx * dx + dy * dy + dz * dz + dw * dw;
  __syncthreads();
  for (int off = 128; off > 0; off >>= 1) {
    if (t < off) red[t] += red[t + off];
    __syncthreads();
  }
  float rs = rsqrtf(red[0] * (1.0f / 1024.0f) + 1e-5f);
  float4 gg = ((const float4*)g)[t];
  if (BF16OUT) {
    usx4 o;
    o.x = f2bf(dx * rs * gg.x); o.y = f2bf(dy * rs * gg.y);
    o.z = f2bf(dz * rs * gg.z); o.w = f2bf(dw * rs * gg.w);
    ((usx4*)(outb + (size_t)rowi * DDIM))[t] = o;
  } else {
    float4 o;
    o.x = dx * rs * gg.x; o.y = dy * rs * gg.y; o.z = dz * rs * gg.z; o.w = dw * rs * gg.w;
    ((float4*)(outf + (size_t)rowi * DDIM))[t] = o;
  }
}

// ---------------- launch ----------------
extern "C" void kernel_launch(void* const* d_in, const int* in_sizes, int n_in,
                              void* d_out, int out_size, void* d_ws, size_t ws_size,
                              hipStream_t stream) {
  (void)in_sizes; (void)n_in; (void)out_size; (void)ws_size;
  const float* x_in       = (const float*)d_in[0];
  const float* attn_w     = (const float*)d_in[1];
  const float* attn_out_w = (const float*)d_in[2];
  const float* mlp_ln_g   = (const float*)d_in[3];
  const float* mlp_in_w   = (const float*)d_in[4];
  const float* mlp_in_b   = (const float*)d_in[5];
  const float* mlp_out_w  = (const float*)d_in[6];
  const float* mlp_out_b  = (const float*)d_in[7];
  const float* skip_w     = (const float*)d_in[8];
  const float* skip_b     = (const float*)d_in[9];
  const float* out_ln_g   = (const float*)d_in[10];

  char* p = (char*)d_ws;
  auto alloc = [&](size_t bytes) { char* r = p; p += (bytes + 255) & ~(size_t)255; return r; };
  float* xbuf = (float*)alloc((size_t)NT * DDIM * 4);
  us* connb = (us*)alloc((size_t)3 * NT * DDIM * 2);   // bf16 skip connections
  us* Qb   = (us*)alloc((size_t)NT * DDIM * 2);
  us* Kb   = (us*)alloc((size_t)NT * DDIM * 2);
  us* Vt   = (us*)alloc((size_t)NT * DDIM * 2);
  us* xbf  = (us*)alloc((size_t)NT * DDIM * 2);
  us* obf  = (us*)alloc((size_t)NT * DDIM * 2);
  us* hln  = (us*)alloc((size_t)NT * DDIM * 2);
  us* hbf  = (us*)alloc((size_t)NT * FF * 2);
  us* wqkv = (us*)alloc((size_t)3 * DDIM * DDIM * 2);
  us* wao  = (us*)alloc((size_t)DDIM * DDIM * 2);
  us* wmi  = (us*)alloc((size_t)FF * DDIM * 2);
  us* wmo  = (us*)alloc((size_t)DDIM * FF * 2);
  us* wsk  = (us*)alloc((size_t)DDIM * 2 * DDIM * 2);

  hipMemcpyAsync(xbuf, x_in, (size_t)NT * DDIM * 4, hipMemcpyDeviceToDevice, stream);
  cast1_kernel<<<1024, 256, 0, stream>>>(x_in, xbf, NT * DDIM / 4);

  for (int i = 0; i < 8; ++i) {
    const int do_skip = (i >= 5);
    cast5_kernel<<<1024, 256, 0, stream>>>(
        attn_w + (size_t)i * 3 * DDIM * DDIM, wqkv, 3 * DDIM * DDIM / 4,
        attn_out_w + (size_t)i * DDIM * DDIM, wao, DDIM * DDIM / 4,
        mlp_in_w + (size_t)i * FF * DDIM, wmi, FF * DDIM / 4,
        mlp_out_w + (size_t)i * DDIM * FF, wmo, DDIM * FF / 4,
        do_skip ? (skip_w + (size_t)(i - 4) * DDIM * 2 * DDIM) : nullptr, wsk,
        do_skip ? (DDIM * 2 * DDIM / 4) : 0);
    if (do_skip) {
      // skip GEMM: x = [x | conn] @ Wsk'^T + skip_b (2^-0.5 folded into Wsk cols>=1024)
      // A split-source: k<1024 from xbf, k>=1024 from connb; writes fp32 xbuf + bf16 xbf
      gemm4<9, 64><<<dim3(16, 32, 1), 256, 0, stream>>>(
          xbf, connb + (size_t)(7 - i) * NT * DDIM, wsk,
          skip_b + (size_t)(i - 4) * DDIM, xbuf, xbf, nullptr, nullptr, nullptr,
          NT, DDIM, 2 * DDIM, 2 * DDIM, DDIM);
    }
    gemm4<5, 128><<<dim3(24, 32, 1), 256, 0, stream>>>(
        xbf, nullptr, wqkv, nullptr, nullptr, nullptr, Qb, Kb, Vt,
        NT, 3 * DDIM, DDIM, DDIM, DDIM);
    attn_mfma_kernel<<<dim3(TT / 64, 2 * NH), 256, 0, stream>>>(Qb, Kb, Vt, obf);
    // attn-out GEMM: xbuf += obf @ Wao^T (non-atomic, z=1)
    gemm4<7, 64><<<dim3(16, 32, 1), 256, 0, stream>>>(
        obf, nullptr, wao, nullptr, xbuf, nullptr, nullptr, nullptr, nullptr,
        NT, DDIM, DDIM, DDIM, DDIM);
    ln_kernel<1><<<NT, 256, 0, stream>>>(xbuf, mlp_ln_g + (size_t)i * DDIM, nullptr, hln);
    gemm4<2, 128><<<dim3(32, 32, 1), 256, 0, stream>>>(
        hln, nullptr, wmi, mlp_in_b + (size_t)i * FF, nullptr, hbf, nullptr, nullptr, nullptr,
        NT, FF, DDIM, DDIM, DDIM);
    // MLP-out GEMM: x = x + h @ Wmo^T + b; writes fp32 xbuf + bf16 xbf (fused bias+resid+cast)
    gemm4<8, 64><<<dim3(16, 32, 1), 256, 0, stream>>>(
        hbf, nullptr, wmo, mlp_out_b + (size_t)i * DDIM, xbuf, xbf, nullptr, nullptr, nullptr,
        NT, DDIM, FF, FF, FF);
    if (i >= 2 && i <= 4)
      hipMemcpyAsync(connb + (size_t)(i - 2) * NT * DDIM, xbf, (size_t)NT * DDIM * 2,
                     hipMemcpyDeviceToDevice, stream);
  }
  ln_kernel<0><<<NT, 256, 0, stream>>>(xbuf, out_ln_g, (float*)d_out, nullptr);
}